// Round 5
// baseline (446.043 us; speedup 1.0000x reference)
//
#include <hip/hip_runtime.h>

// MoleculeGCN: 2-layer GCN, N=100000, 128->64->64, E=1600000 + self-loops.
// CSR-by-dst with interleaved {src,norm} 8B records (halves scatter-write line
// amplification vs two 4B arrays). Raw edge words read directly (no src32/dst32
// intermediate). GEMM1 fused into the count pass (independent work, hides under
// the memory-bound degree count).

#define GSB 2048  // grid-stride blocks for edge-parallel work

// ---------- edge dtype detect (int64 vs int32), SAMPLED ----------
// int64: odd 32-bit words are high halves of node ids (< 2^17) -> all zero.
// int32: odd words are random node ids -> 16384 all-zero samples impossible.
__global__ __launch_bounds__(256) void detect_dtype_kernel(const unsigned* __restrict__ w,
                                                           int E, unsigned* __restrict__ flag) {
  __shared__ unsigned sacc;
  if (threadIdx.x == 0) sacc = 0u;
  __syncthreads();
  int ns = min(16384, E);
  unsigned acc = 0;
  for (int i = threadIdx.x; i < ns; i += 256) acc |= w[2 * i + 1];
  if (__any(acc != 0) && (threadIdx.x & 63) == 0) sacc = 1u;  // LDS, not global atomic
  __syncthreads();
  if (threadIdx.x == 0) *flag = sacc;
}

__device__ __forceinline__ int edge_src(const int* w, long e, long E, bool is64) {
  return is64 ? w[2 * e] : w[e];
}
__device__ __forceinline__ int edge_dst(const int* w, long e, long E, bool is64) {
  return is64 ? w[2 * (E + e)] : w[E + e];
}

// ---------- fused: in-degree count (blocks [0,GSB)) + GEMM1 (rest) ----------
// Independent work items: count reads edges/atomics cnt; gemm reads x/W1 and
// writes h1. Fusing overlaps the VALU-bound GEMM with the memory-bound count.
__global__ __launch_bounds__(256) void count_gemm1_kernel(
    const int* __restrict__ w, int E, const unsigned* __restrict__ flag,
    int* __restrict__ cnt,
    const float* __restrict__ X, const float* __restrict__ W,
    float* __restrict__ H, int n) {
  if (blockIdx.x < GSB) {  // ---- degree count over dst stream ----
    bool is64 = (*flag == 0u);
    int stride = GSB * 256;
    for (int e = blockIdx.x * 256 + threadIdx.x; e < E; e += stride)
      atomicAdd(&cnt[edge_dst(w, e, E, is64)], 1);
    return;
  }
  // ---- GEMM1: H[n][64] = X[n][128] @ W[128][64] ----
  __shared__ float Ws[128 * 64];
  for (int i = threadIdx.x; i < 128 * 64; i += 256) Ws[i] = W[i];
  __syncthreads();
  int row = (blockIdx.x - GSB) * 256 + threadIdx.x;
  if (row >= n) return;
  const float4* xr = (const float4*)(X + (size_t)row * 128);
  float acc[64];
#pragma unroll
  for (int c = 0; c < 64; c++) acc[c] = 0.f;
#pragma unroll 4
  for (int k4 = 0; k4 < 32; k4++) {
    float4 xv = xr[k4];
#pragma unroll
    for (int kk = 0; kk < 4; kk++) {
      float xs = (kk == 0) ? xv.x : (kk == 1) ? xv.y : (kk == 2) ? xv.z : xv.w;
      const float4* wr = (const float4*)&Ws[(k4 * 4 + kk) * 64];
#pragma unroll
      for (int c4 = 0; c4 < 16; c4++) {
        float4 wv = wr[c4];  // same address across lanes -> LDS broadcast
        acc[c4 * 4 + 0] += xs * wv.x;
        acc[c4 * 4 + 1] += xs * wv.y;
        acc[c4 * 4 + 2] += xs * wv.z;
        acc[c4 * 4 + 3] += xs * wv.w;
      }
    }
  }
  float4* ho = (float4*)(H + (size_t)row * 64);
#pragma unroll
  for (int c4 = 0; c4 < 16; c4++) {
    float4 v;
    v.x = acc[c4 * 4 + 0]; v.y = acc[c4 * 4 + 1];
    v.z = acc[c4 * 4 + 2]; v.w = acc[c4 * 4 + 3];
    ho[c4] = v;
  }
}

// ---------- exclusive scan over cnt[N] -> offs[N+1] ----------
#define SCAN_BS 256
__global__ void scan_block_kernel(const int* __restrict__ cnt, int n, int* __restrict__ bsums) {
  __shared__ int s[SCAN_BS];
  int gid = blockIdx.x * SCAN_BS + threadIdx.x;
  s[threadIdx.x] = (gid < n) ? cnt[gid] : 0;
  __syncthreads();
  for (int st = SCAN_BS / 2; st > 0; st >>= 1) {
    if (threadIdx.x < st) s[threadIdx.x] += s[threadIdx.x + st];
    __syncthreads();
  }
  if (threadIdx.x == 0) bsums[blockIdx.x] = s[0];
}

// parallel single-block exclusive scan of bsums (chunked Hillis-Steele)
__global__ __launch_bounds__(512) void scan_bsums_kernel(int* __restrict__ bsums, int nb) {
  __shared__ int s[512];
  int carry = 0;
  for (int base = 0; base < nb; base += 512) {
    int g = base + threadIdx.x;
    int v = (g < nb) ? bsums[g] : 0;
    s[threadIdx.x] = v;
    __syncthreads();
    for (int st = 1; st < 512; st <<= 1) {
      int t = (threadIdx.x >= st) ? s[threadIdx.x - st] : 0;
      __syncthreads();
      s[threadIdx.x] += t;
      __syncthreads();
    }
    if (g < nb) bsums[g] = carry + s[threadIdx.x] - v;  // exclusive
    carry += s[511];
    __syncthreads();
  }
}

// offs (exclusive scan of cnt, + sentinel offs[n]=E) + dinv (fused)
__global__ void scan_apply_kernel(const int* __restrict__ cnt, int n,
                                  const int* __restrict__ bsums, int* __restrict__ offs,
                                  float* __restrict__ dinv, int E) {
  __shared__ int s[SCAN_BS];
  int gid = blockIdx.x * SCAN_BS + threadIdx.x;
  int v = (gid < n) ? cnt[gid] : 0;
  s[threadIdx.x] = v;
  __syncthreads();
  for (int st = 1; st < SCAN_BS; st <<= 1) {
    int t = (threadIdx.x >= st) ? s[threadIdx.x - st] : 0;
    __syncthreads();
    s[threadIdx.x] += t;
    __syncthreads();
  }
  if (gid < n) {
    offs[gid] = bsums[blockIdx.x] + s[threadIdx.x] - v;  // exclusive
    dinv[gid] = rsqrtf((float)v + 1.0f);                 // +1 = self loop
    if (gid == n - 1) offs[n] = E;                       // sentinel
  }
}

// ---------- counting-sort scatter: CSR by dst, 8B interleaved records ----------
// One dwordx2 store per edge -> one dirty line per edge (round-4 version dirtied
// two lines per edge across csrc[]/cnorm[]: WRITE_SIZE 156MB for 12.8MB payload).
__global__ void build_csr_kernel(const int* __restrict__ w, int E,
                                 const unsigned* __restrict__ flag,
                                 const int* __restrict__ offs, int* __restrict__ fill,
                                 const float* __restrict__ dinv,
                                 int2* __restrict__ csr) {
  bool is64 = (*flag == 0u);
  int stride = gridDim.x * blockDim.x;
  for (int e = blockIdx.x * blockDim.x + threadIdx.x; e < E; e += stride) {
    int s = edge_src(w, e, E, is64);
    int d = edge_dst(w, e, E, is64);
    int pos = offs[d] + atomicAdd(&fill[d], 1);
    int2 rec;
    rec.x = s;
    rec.y = __float_as_int(dinv[s] * dinv[d]);
    csr[pos] = rec;
  }
}

// ---------- aggregation: one wave per node, lane = feature ----------
// 8B records loaded COALESCED by the 64 lanes, broadcast via shuffle;
// 16 row-gathers kept in flight; tail padded with (src=0, norm=0).
__global__ __launch_bounds__(256) void aggregate_kernel(
    const float* __restrict__ H, const int* __restrict__ offs,
    const int2* __restrict__ csr,
    const float* __restrict__ dinv, const float* __restrict__ bias,
    float* __restrict__ OUT, int n, int relu) {
  int wid = (blockIdx.x * 256 + threadIdx.x) >> 6;
  int lane = threadIdx.x & 63;
  if (wid >= n) return;
  float bv = bias[lane];
  float di = dinv[wid];
  int beg = offs[wid];
  int end = offs[wid + 1];
  float acc = H[(size_t)wid * 64 + lane] * (di * di);  // self loop
  for (int base = beg; base < end; base += 64) {
    int m = min(64, end - base);
    int sl = 0; float nl = 0.f;
    if (lane < m) {
      int2 rec = csr[base + lane];  // coalesced 8B
      sl = rec.x;
      nl = __int_as_float(rec.y);
    }
    int mr = (m + 15) & ~15;  // pad to 16: lanes >= m carry (0, 0.0f) -> no-op
    for (int j = 0; j < mr; j += 16) {
      int s[16]; float w[16]; float h[16];
#pragma unroll
      for (int t = 0; t < 16; t++) {
        s[t] = __shfl(sl, j + t);
        w[t] = __shfl(nl, j + t);
      }
#pragma unroll
      for (int t = 0; t < 16; t++) h[t] = H[(size_t)s[t] * 64 + lane];  // 16 in flight
#pragma unroll
      for (int t = 0; t < 16; t++) acc += h[t] * w[t];
    }
  }
  acc += bv;
  if (relu) acc = fmaxf(acc, 0.f);
  OUT[(size_t)wid * 64 + lane] = acc;
}

// ---------- GEMM2 (standalone): H[n][64] = X[n][64] @ W[64][64] ----------
__global__ __launch_bounds__(256) void gemm2_kernel(const float* __restrict__ X,
                                                    const float* __restrict__ W,
                                                    float* __restrict__ H, int n) {
  __shared__ float Ws[64 * 64];
  for (int i = threadIdx.x; i < 64 * 64; i += 256) Ws[i] = W[i];
  __syncthreads();
  int row = blockIdx.x * 256 + threadIdx.x;
  if (row >= n) return;
  const float4* xr = (const float4*)(X + (size_t)row * 64);
  float acc[64];
#pragma unroll
  for (int c = 0; c < 64; c++) acc[c] = 0.f;
#pragma unroll 4
  for (int k4 = 0; k4 < 16; k4++) {
    float4 xv = xr[k4];
#pragma unroll
    for (int kk = 0; kk < 4; kk++) {
      float xs = (kk == 0) ? xv.x : (kk == 1) ? xv.y : (kk == 2) ? xv.z : xv.w;
      const float4* wr = (const float4*)&Ws[(k4 * 4 + kk) * 64];
#pragma unroll
      for (int c4 = 0; c4 < 16; c4++) {
        float4 wv = wr[c4];
        acc[c4 * 4 + 0] += xs * wv.x;
        acc[c4 * 4 + 1] += xs * wv.y;
        acc[c4 * 4 + 2] += xs * wv.z;
        acc[c4 * 4 + 3] += xs * wv.w;
      }
    }
  }
  float4* ho = (float4*)(H + (size_t)row * 64);
#pragma unroll
  for (int c4 = 0; c4 < 16; c4++) {
    float4 v;
    v.x = acc[c4 * 4 + 0]; v.y = acc[c4 * 4 + 1];
    v.z = acc[c4 * 4 + 2]; v.w = acc[c4 * 4 + 3];
    ho[c4] = v;
  }
}

extern "C" void kernel_launch(void* const* d_in, const int* in_sizes, int n_in,
                              void* d_out, int out_size, void* d_ws, size_t ws_size,
                              hipStream_t stream) {
  const float* x  = (const float*)d_in[0];
  const int*   ei = (const int*)d_in[1];
  const float* W1 = (const float*)d_in[2];
  const float* b1 = (const float*)d_in[3];
  const float* W2 = (const float*)d_in[4];
  const float* b2 = (const float*)d_in[5];
  float* out = (float*)d_out;

  const int N = in_sizes[0] / 128;
  const int E = in_sizes[1] / 2;

  // ---- workspace carve-up (256B aligned) ----
  size_t off = 0;
  char* base = (char*)d_ws;
  auto alloc = [&](size_t bytes) -> void* {
    void* p = base + off;
    off += (bytes + 255) & ~(size_t)255;
    return p;
  };
  int*      cnt  = (int*)alloc((size_t)N * 4);      // } zeroed as one region
  int*      fill = (int*)alloc((size_t)N * 4);      // }
  unsigned* flag = (unsigned*)alloc(256);           // }
  size_t zero_bytes = off;
  int*   offs  = (int*)alloc((size_t)(N + 1) * 4);
  float* dinv  = (float*)alloc((size_t)N * 4);
  int nb = (N + SCAN_BS - 1) / SCAN_BS;
  int*   bsums = (int*)alloc((size_t)nb * 4);
  int2*  csr   = (int2*)alloc((size_t)E * 8);
  float* h1    = (float*)alloc((size_t)N * 64 * 4);
  float* a1    = (float*)alloc((size_t)N * 64 * 4);
  float* h2    = h1;  // h1 dead after first aggregation

  hipMemsetAsync(d_ws, 0, zero_bytes, stream);

  int gemm_blocks = (N + 255) / 256;

  // ---- graph prep + GEMM1 (fused: count || gemm1, independent) ----
  detect_dtype_kernel<<<1, 256, 0, stream>>>((const unsigned*)ei, E, flag);
  count_gemm1_kernel<<<GSB + gemm_blocks, 256, 0, stream>>>(ei, E, flag, cnt, x, W1, h1, N);
  scan_block_kernel<<<nb, SCAN_BS, 0, stream>>>(cnt, N, bsums);
  scan_bsums_kernel<<<1, 512, 0, stream>>>(bsums, nb);
  scan_apply_kernel<<<nb, SCAN_BS, 0, stream>>>(cnt, N, bsums, offs, dinv, E);
  build_csr_kernel<<<GSB, 256, 0, stream>>>(ei, E, flag, offs, fill, dinv, csr);

  // ---- layer 1 aggregation ----
  aggregate_kernel<<<(N + 3) / 4, 256, 0, stream>>>(h1, offs, csr, dinv, b1, a1, N, 1);

  // ---- layer 2 ----
  gemm2_kernel<<<gemm_blocks, 256, 0, stream>>>(a1, W2, h2, N);
  aggregate_kernel<<<(N + 3) / 4, 256, 0, stream>>>(h2, offs, csr, dinv, b2, out, N, 0);
}

// Round 6
// 434.735 us; speedup vs baseline: 1.0260x; 1.0260x over previous
//
#include <hip/hip_runtime.h>

// MoleculeGCN: 2-layer GCN, N=100000, 128->64->64, E=1600000 + self-loops.
// CSR-by-dst with interleaved {src,norm} 8B records. Raw edge words read
// directly. Count and GEMM1 are SEPARATE kernels (round-5 fusion made all
// count blocks reserve the GEMM's 32KB LDS -> occupancy 21% -> 123us).
// Aggregation: 4 edge-groups x 16 lanes x float4 per wave (32 edges in
// flight, 4x fewer shuffles than lane-per-feature).

#define GSB 2048  // grid-stride blocks for edge-parallel work

// ---------- edge dtype detect (int64 vs int32), SAMPLED ----------
// int64: odd 32-bit words are high halves of node ids (< 2^17) -> all zero.
// int32: odd words are random node ids -> 16384 all-zero samples impossible.
__global__ __launch_bounds__(256) void detect_dtype_kernel(const unsigned* __restrict__ w,
                                                           int E, unsigned* __restrict__ flag) {
  __shared__ unsigned sacc;
  if (threadIdx.x == 0) sacc = 0u;
  __syncthreads();
  int ns = min(16384, E);
  unsigned acc = 0;
  for (int i = threadIdx.x; i < ns; i += 256) acc |= w[2 * i + 1];
  if (__any(acc != 0) && (threadIdx.x & 63) == 0) sacc = 1u;  // LDS, not global atomic
  __syncthreads();
  if (threadIdx.x == 0) *flag = sacc;
}

__device__ __forceinline__ int edge_src(const int* w, long e, long E, bool is64) {
  return is64 ? w[2 * e] : w[e];
}
__device__ __forceinline__ int edge_dst(const int* w, long e, long E, bool is64) {
  return is64 ? w[2 * (E + e)] : w[E + e];
}

// ---------- in-degree count (no LDS, full occupancy) ----------
__global__ __launch_bounds__(256) void count_deg_kernel(const int* __restrict__ w, int E,
                                                        const unsigned* __restrict__ flag,
                                                        int* __restrict__ cnt) {
  bool is64 = (*flag == 0u);
  int stride = gridDim.x * blockDim.x;
  for (int e = blockIdx.x * blockDim.x + threadIdx.x; e < E; e += stride)
    atomicAdd(&cnt[edge_dst(w, e, E, is64)], 1);
}

// ---------- exclusive scan over cnt[N] -> offs[N+1] ----------
#define SCAN_BS 256
__global__ void scan_block_kernel(const int* __restrict__ cnt, int n, int* __restrict__ bsums) {
  __shared__ int s[SCAN_BS];
  int gid = blockIdx.x * SCAN_BS + threadIdx.x;
  s[threadIdx.x] = (gid < n) ? cnt[gid] : 0;
  __syncthreads();
  for (int st = SCAN_BS / 2; st > 0; st >>= 1) {
    if (threadIdx.x < st) s[threadIdx.x] += s[threadIdx.x + st];
    __syncthreads();
  }
  if (threadIdx.x == 0) bsums[blockIdx.x] = s[0];
}

// parallel single-block exclusive scan of bsums (chunked Hillis-Steele)
__global__ __launch_bounds__(512) void scan_bsums_kernel(int* __restrict__ bsums, int nb) {
  __shared__ int s[512];
  int carry = 0;
  for (int base = 0; base < nb; base += 512) {
    int g = base + threadIdx.x;
    int v = (g < nb) ? bsums[g] : 0;
    s[threadIdx.x] = v;
    __syncthreads();
    for (int st = 1; st < 512; st <<= 1) {
      int t = (threadIdx.x >= st) ? s[threadIdx.x - st] : 0;
      __syncthreads();
      s[threadIdx.x] += t;
      __syncthreads();
    }
    if (g < nb) bsums[g] = carry + s[threadIdx.x] - v;  // exclusive
    carry += s[511];
    __syncthreads();
  }
}

// offs (exclusive scan of cnt, + sentinel offs[n]=E) + dinv (fused)
__global__ void scan_apply_kernel(const int* __restrict__ cnt, int n,
                                  const int* __restrict__ bsums, int* __restrict__ offs,
                                  float* __restrict__ dinv, int E) {
  __shared__ int s[SCAN_BS];
  int gid = blockIdx.x * SCAN_BS + threadIdx.x;
  int v = (gid < n) ? cnt[gid] : 0;
  s[threadIdx.x] = v;
  __syncthreads();
  for (int st = 1; st < SCAN_BS; st <<= 1) {
    int t = (threadIdx.x >= st) ? s[threadIdx.x - st] : 0;
    __syncthreads();
    s[threadIdx.x] += t;
    __syncthreads();
  }
  if (gid < n) {
    offs[gid] = bsums[blockIdx.x] + s[threadIdx.x] - v;  // exclusive
    dinv[gid] = rsqrtf((float)v + 1.0f);                 // +1 = self loop
    if (gid == n - 1) offs[n] = E;                       // sentinel
  }
}

// ---------- counting-sort scatter: CSR by dst, 8B interleaved records ----------
__global__ void build_csr_kernel(const int* __restrict__ w, int E,
                                 const unsigned* __restrict__ flag,
                                 const int* __restrict__ offs, int* __restrict__ fill,
                                 const float* __restrict__ dinv,
                                 int2* __restrict__ csr) {
  bool is64 = (*flag == 0u);
  int stride = gridDim.x * blockDim.x;
  for (int e = blockIdx.x * blockDim.x + threadIdx.x; e < E; e += stride) {
    int s = edge_src(w, e, E, is64);
    int d = edge_dst(w, e, E, is64);
    int pos = offs[d] + atomicAdd(&fill[d], 1);
    int2 rec;
    rec.x = s;
    rec.y = __float_as_int(dinv[s] * dinv[d]);
    csr[pos] = rec;
  }
}

// ---------- GEMM: H[n][64] = X[n][K] @ W[K][64], W staged in LDS ----------
template <int K>
__global__ __launch_bounds__(256) void gemm_kernel(const float* __restrict__ X,
                                                   const float* __restrict__ W,
                                                   float* __restrict__ H, int n) {
  __shared__ float Ws[K * 64];
  for (int i = threadIdx.x; i < K * 64; i += 256) Ws[i] = W[i];
  __syncthreads();
  int row = blockIdx.x * 256 + threadIdx.x;
  if (row >= n) return;
  const float4* xr = (const float4*)(X + (size_t)row * K);
  float acc[64];
#pragma unroll
  for (int c = 0; c < 64; c++) acc[c] = 0.f;
#pragma unroll 4
  for (int k4 = 0; k4 < K / 4; k4++) {
    float4 xv = xr[k4];
#pragma unroll
    for (int kk = 0; kk < 4; kk++) {
      float xs = (kk == 0) ? xv.x : (kk == 1) ? xv.y : (kk == 2) ? xv.z : xv.w;
      const float4* wr = (const float4*)&Ws[(k4 * 4 + kk) * 64];
#pragma unroll
      for (int c4 = 0; c4 < 16; c4++) {
        float4 wv = wr[c4];  // same address across lanes -> LDS broadcast
        acc[c4 * 4 + 0] += xs * wv.x;
        acc[c4 * 4 + 1] += xs * wv.y;
        acc[c4 * 4 + 2] += xs * wv.z;
        acc[c4 * 4 + 3] += xs * wv.w;
      }
    }
  }
  float4* ho = (float4*)(H + (size_t)row * 64);
#pragma unroll
  for (int c4 = 0; c4 < 16; c4++) {
    float4 v;
    v.x = acc[c4 * 4 + 0]; v.y = acc[c4 * 4 + 1];
    v.z = acc[c4 * 4 + 2]; v.w = acc[c4 * 4 + 3];
    ho[c4] = v;
  }
}

// ---------- aggregation: one wave per node, 4 edge-groups x 16 lanes x float4 ----
// Wave layout: grp = lane>>4 (edge subset), fl = lane&15 (float4 of the row).
// Each 16-lane group reads one 256B H-row per iteration (coalesced); 8-deep
// unroll x 4 groups = 32 edges in flight. Cross-group shfl_xor reduce at end;
// lanes 0-15 add self-loop + bias and write one coalesced 256B row.
__global__ __launch_bounds__(256) void aggregate_kernel(
    const float4* __restrict__ H4, const int* __restrict__ offs,
    const int2* __restrict__ csr,
    const float* __restrict__ dinv, const float4* __restrict__ bias4,
    float4* __restrict__ OUT4, int n, int relu) {
  int wid = (blockIdx.x * 256 + threadIdx.x) >> 6;
  int lane = threadIdx.x & 63;
  if (wid >= n) return;
  int grp = lane >> 4;
  int fl = lane & 15;
  int beg = offs[wid];
  int end = offs[wid + 1];
  float4 acc = {0.f, 0.f, 0.f, 0.f};
  for (int base = beg; base < end; base += 64) {
    int m = min(64, end - base);
    int sl = 0; float nl = 0.f;
    if (lane < m) {
      int2 rec = csr[base + lane];  // coalesced 8B
      sl = rec.x;
      nl = __int_as_float(rec.y);
    }
    int iters = ((m + 31) >> 5) << 3;  // 8 or 16; each iter covers 4 edges
    for (int j0 = 0; j0 < iters; j0 += 8) {
      int s[8]; float w[8]; float4 h[8];
#pragma unroll
      for (int t = 0; t < 8; t++) {
        int idx = (j0 + t) * 4 + grp;  // uniform within each 16-lane group
        s[t] = __shfl(sl, idx);
        w[t] = __shfl(nl, idx);
      }
#pragma unroll
      for (int t = 0; t < 8; t++) h[t] = H4[(size_t)s[t] * 16 + fl];  // 8 in flight/lane
#pragma unroll
      for (int t = 0; t < 8; t++) {
        acc.x += h[t].x * w[t];
        acc.y += h[t].y * w[t];
        acc.z += h[t].z * w[t];
        acc.w += h[t].w * w[t];
      }
    }
  }
  // reduce the 4 group-partials (lanes fl, fl+16, fl+32, fl+48)
#pragma unroll
  for (int off2 = 32; off2 >= 16; off2 >>= 1) {
    acc.x += __shfl_xor(acc.x, off2);
    acc.y += __shfl_xor(acc.y, off2);
    acc.z += __shfl_xor(acc.z, off2);
    acc.w += __shfl_xor(acc.w, off2);
  }
  if (lane < 16) {
    float di = dinv[wid];
    float d2 = di * di;
    float4 hv = H4[(size_t)wid * 16 + fl];
    float4 bv = bias4[fl];
    acc.x += hv.x * d2 + bv.x;
    acc.y += hv.y * d2 + bv.y;
    acc.z += hv.z * d2 + bv.z;
    acc.w += hv.w * d2 + bv.w;
    if (relu) {
      acc.x = fmaxf(acc.x, 0.f);
      acc.y = fmaxf(acc.y, 0.f);
      acc.z = fmaxf(acc.z, 0.f);
      acc.w = fmaxf(acc.w, 0.f);
    }
    OUT4[(size_t)wid * 16 + fl] = acc;  // 16 lanes x 16B = coalesced 256B row
  }
}

extern "C" void kernel_launch(void* const* d_in, const int* in_sizes, int n_in,
                              void* d_out, int out_size, void* d_ws, size_t ws_size,
                              hipStream_t stream) {
  const float* x  = (const float*)d_in[0];
  const int*   ei = (const int*)d_in[1];
  const float* W1 = (const float*)d_in[2];
  const float* b1 = (const float*)d_in[3];
  const float* W2 = (const float*)d_in[4];
  const float* b2 = (const float*)d_in[5];
  float* out = (float*)d_out;

  const int N = in_sizes[0] / 128;
  const int E = in_sizes[1] / 2;

  // ---- workspace carve-up (256B aligned) ----
  size_t off = 0;
  char* base = (char*)d_ws;
  auto alloc = [&](size_t bytes) -> void* {
    void* p = base + off;
    off += (bytes + 255) & ~(size_t)255;
    return p;
  };
  int*      cnt  = (int*)alloc((size_t)N * 4);      // } zeroed as one region
  int*      fill = (int*)alloc((size_t)N * 4);      // }
  unsigned* flag = (unsigned*)alloc(256);           // }
  size_t zero_bytes = off;
  int*   offs  = (int*)alloc((size_t)(N + 1) * 4);
  float* dinv  = (float*)alloc((size_t)N * 4);
  int nb = (N + SCAN_BS - 1) / SCAN_BS;
  int*   bsums = (int*)alloc((size_t)nb * 4);
  int2*  csr   = (int2*)alloc((size_t)E * 8);
  float* h1    = (float*)alloc((size_t)N * 64 * 4);
  float* a1    = (float*)alloc((size_t)N * 64 * 4);
  float* h2    = h1;  // h1 dead after first aggregation

  hipMemsetAsync(d_ws, 0, zero_bytes, stream);

  int gemm_blocks = (N + 255) / 256;
  int agg_blocks = (N + 3) / 4;

  // ---- graph prep (shared by both layers) ----
  detect_dtype_kernel<<<1, 256, 0, stream>>>((const unsigned*)ei, E, flag);
  count_deg_kernel<<<GSB, 256, 0, stream>>>(ei, E, flag, cnt);
  scan_block_kernel<<<nb, SCAN_BS, 0, stream>>>(cnt, N, bsums);
  scan_bsums_kernel<<<1, 512, 0, stream>>>(bsums, nb);
  scan_apply_kernel<<<nb, SCAN_BS, 0, stream>>>(cnt, N, bsums, offs, dinv, E);
  build_csr_kernel<<<GSB, 256, 0, stream>>>(ei, E, flag, offs, fill, dinv, csr);

  // ---- layer 1 ----
  gemm_kernel<128><<<gemm_blocks, 256, 0, stream>>>(x, W1, h1, N);
  aggregate_kernel<<<agg_blocks, 256, 0, stream>>>(
      (const float4*)h1, offs, csr, dinv, (const float4*)b1, (float4*)a1, N, 1);

  // ---- layer 2 ----
  gemm_kernel<64><<<gemm_blocks, 256, 0, stream>>>(a1, W2, h2, N);
  aggregate_kernel<<<agg_blocks, 256, 0, stream>>>(
      (const float4*)h2, offs, csr, dinv, (const float4*)b2, (float4*)out, N, 0);
}